// Round 10
// baseline (602.230 us; speedup 1.0000x reference)
//
#include <hip/hip_runtime.h>

#define NT 512
#define DIN 7
#define CTC 64
#define HSTR 72       // f16 stride per sample row: 64 data + 8 pad = 144 B
#define NGRP 2        // independent 16-sample groups per block
#define NBATCH 2048

typedef _Float16 half4 __attribute__((ext_vector_type(4)));
typedef _Float16 half8 __attribute__((ext_vector_type(8)));
typedef float    f32x4 __attribute__((ext_vector_type(4)));

#define MFMA32(A, B, C) __builtin_amdgcn_mfma_f32_16x16x32_f16((A), (B), (C), 0, 0, 0)

__device__ __forceinline__ float rcp_fast(float x) { return __builtin_amdgcn_rcpf(x); }
__device__ __forceinline__ float sigm(float x)     { return rcp_fast(1.0f + __expf(-x)); }
__device__ __forceinline__ float tanh_fast(float v) {
  return fmaf(-2.0f, rcp_fast(1.0f + __expf(2.0f * v)), 1.0f);  // inf-safe both ends
}

// 16 waves / block, 2 independent 16-sample groups, 64 blocks. Per group:
// waves 0-3 layer0(tick k), waves 4-7 layer1(tick k-1). 4 waves/SIMD with
// independent stall patterns -> latency hiding (recurrence is latency-bound;
// idle CUs are worthless, resident waves are not). Operand-swapped MFMA
// (D = W·h^T, bias in C); h carried in fp32 registers by the owning lane;
// f16 copy exchanged via LDS. ONE barrier per tick.
__global__ __launch_bounds__(1024, 1) void gru16(
    const float* __restrict__ x,     // [B][T][7]
    const float* __restrict__ Wih0,  // [192][7]
    const float* __restrict__ Whh0,  // [192][64]
    const float* __restrict__ bih0,  // [192]
    const float* __restrict__ bhh0,  // [192]
    const float* __restrict__ Wih1,  // [192][64]
    const float* __restrict__ Whh1,  // [192][64]
    const float* __restrict__ bih1,  // [192]
    const float* __restrict__ bhh1,  // [192]
    const float* __restrict__ fcW,   // [64]
    const float* __restrict__ fcb,   // [1]
    float* __restrict__ out)         // [2048]
{
  __shared__ __align__(16) _Float16 H0[NGRP][2][16][HSTR];
  __shared__ __align__(16) _Float16 H1[NGRP][2][16][HSTR];
  __shared__ __align__(16) _Float16 xb[NGRP][16][CTC + 1][8];
  __shared__ float red[NGRP][4][16];

  const int tid = threadIdx.x;
  const int grp = tid >> 9;        // group 0/1
  const int t9  = tid & 511;
  const int col = tid & 15;        // sample / fragment col
  const int q   = (tid >> 4) & 3;  // k-octet / D-row quad
  const int wv  = t9 >> 6;         // 0..7 within group
  const bool isL0 = (wv < 4);
  const int w   = wv & 3;          // gate-tile group 0..3
  const int s0  = blockIdx.x * (16 * NGRP) + grp * 16;

  for (int i = tid; i < NGRP * 2 * 16 * HSTR; i += 1024) {
    ((_Float16*)H0)[i] = (_Float16)0; ((_Float16*)H1)[i] = (_Float16)0;
  }

  // group-local LDS views (address math, not register indexing)
  _Float16 (*H0g)[16][HSTR] = H0[grp];
  _Float16 (*H1g)[16][HSTR] = H1[grp];
  _Float16 (*xbg)[CTC + 1][8] = xb[grp];

  const int gr = w * 16 + col, gz = (4 + w) * 16 + col, gn = (8 + w) * 16 + col;
  const int bo = w * 16 + 4 * q;   // this lane's D-row gate offset (within 64)

  // ---- biases in registers (C-operand of the first MFMA in each chain) ----
  f32x4 bR, bZ, bXN, bHN;
  {
    const float* bi = isL0 ? bih0 : bih1;
    const float* bh = isL0 ? bhh0 : bhh1;
    f32x4 t1 = *(const f32x4*)&bi[bo],       t2 = *(const f32x4*)&bh[bo];
    bR = t1 + t2;
    t1 = *(const f32x4*)&bi[64 + bo];        t2 = *(const f32x4*)&bh[64 + bo];
    bZ = t1 + t2;
    bXN = *(const f32x4*)&bi[128 + bo];
    bHN = *(const f32x4*)&bh[128 + bo];
  }

  // ---- weight A-fragments: lane holds W[g][k = 32*kt + 8*q + i], i=0..7 ----
  half8 Wa0 = {}, Wa1 = {}, Wa2 = {};           // L0: Wih0 r/z/n (q==0 lanes only)
  half8 A0k0, A0k1, A1k0, A1k1, A2k0, A2k1;     // L0: Whh0 | L1: Wih1
  half8 B0k0 = {}, B0k1 = {}, B1k0 = {}, B1k1 = {}, B2k0 = {}, B2k1 = {}; // L1: Whh1

#define LDW8(dst, W, g, kt) do {                                   \
    f32x4 _a = *(const f32x4*)&(W)[(g) * 64 + 32 * (kt) + 8 * q];  \
    f32x4 _b = *(const f32x4*)&(W)[(g) * 64 + 32 * (kt) + 8 * q + 4]; \
    half8 _h;                                                       \
    _h[0] = (_Float16)_a[0]; _h[1] = (_Float16)_a[1];               \
    _h[2] = (_Float16)_a[2]; _h[3] = (_Float16)_a[3];               \
    _h[4] = (_Float16)_b[0]; _h[5] = (_Float16)_b[1];               \
    _h[6] = (_Float16)_b[2]; _h[7] = (_Float16)_b[3];               \
    (dst) = _h;                                                     \
  } while (0)

  if (isL0) {
    if (q == 0) {
#pragma unroll
      for (int i = 0; i < DIN; ++i) {
        Wa0[i] = (_Float16)Wih0[gr * DIN + i];
        Wa1[i] = (_Float16)Wih0[gz * DIN + i];
        Wa2[i] = (_Float16)Wih0[gn * DIN + i];
      }
    }
    LDW8(A0k0, Whh0, gr, 0); LDW8(A0k1, Whh0, gr, 1);
    LDW8(A1k0, Whh0, gz, 0); LDW8(A1k1, Whh0, gz, 1);
    LDW8(A2k0, Whh0, gn, 0); LDW8(A2k1, Whh0, gn, 1);
  } else {
    LDW8(A0k0, Wih1, gr, 0); LDW8(A0k1, Wih1, gr, 1);
    LDW8(A1k0, Wih1, gz, 0); LDW8(A1k1, Wih1, gz, 1);
    LDW8(A2k0, Wih1, gn, 0); LDW8(A2k1, Wih1, gn, 1);
    LDW8(B0k0, Whh1, gr, 0); LDW8(B0k1, Whh1, gr, 1);
    LDW8(B1k0, Whh1, gz, 0); LDW8(B1k1, Whh1, gz, 1);
    LDW8(B2k0, Whh1, gn, 0); LDW8(B2k1, Whh1, gn, 1);
  }
#undef LDW8
  __syncthreads();

  // lane's own h slice [16w+4q, +4), fp32, carried across ticks (exact)
  f32x4 hown = (f32x4){};

  // ticks k = 0..NT: L0 computes h0(k) (k<NT), L1 computes h1(k-1) (k>0).
  for (int k = 0; k <= NT; ++k) {
    const int p = k & 1;

    if ((k & (CTC - 1)) == 0 && k < NT) {
      // ---- stage CTC-step x chunk per group (512 threads/group) ----
      for (int e = t9; e < 16 * CTC; e += 512) {
        const int ss = e & 15, tt = e >> 4;
        const float* xp = x + ((size_t)(s0 + ss) * NT + k + tt) * DIN;
        half8 v = (half8){};
#pragma unroll
        for (int d = 0; d < DIN; ++d) v[d] = (_Float16)xp[d];
        *(half8*)&xbg[ss][tt][0] = v;
      }
      __syncthreads();
    }

    if (isL0) {
      if (k < NT) {
        const int ti = k & (CTC - 1);
        half8 hh0 = *(const half8*)&H0g[p][col][ 0 + 8 * q];
        half8 hh1 = *(const half8*)&H0g[p][col][32 + 8 * q];
        half8 xf = (half8){};
        if (q == 0) xf = *(const half8*)&xbg[col][ti][0];

        f32x4 ar  = MFMA32(A0k0, hh0, MFMA32(Wa0, xf, bR));
        f32x4 ar2 = MFMA32(A0k1, hh1, (f32x4){});
        f32x4 az  = MFMA32(A1k0, hh0, MFMA32(Wa1, xf, bZ));
        f32x4 az2 = MFMA32(A1k1, hh1, (f32x4){});
        f32x4 axn = MFMA32(Wa2, xf, bXN);
        f32x4 ahn = MFMA32(A2k0, hh0, bHN);
        f32x4 ahn2 = MFMA32(A2k1, hh1, (f32x4){});
        ar += ar2; az += az2; ahn += ahn2;

        half4 nh;
#pragma unroll
        for (int i = 0; i < 4; ++i) {
          const float r = sigm(ar[i]);
          const float z = sigm(az[i]);
          const float n = tanh_fast(fmaf(r, ahn[i], axn[i]));
          hown[i] = fmaf(z, hown[i] - n, n);     // exact fp32 recurrence
          nh[i] = (_Float16)hown[i];
        }
        *(half4*)&H0g[p ^ 1][col][16 * w + 4 * q] = nh;
      }
    } else {
      if (k > 0) {
        half8 g0h0 = *(const half8*)&H0g[p][col][ 0 + 8 * q];
        half8 g0h1 = *(const half8*)&H0g[p][col][32 + 8 * q];
        half8 g1h0 = *(const half8*)&H1g[p ^ 1][col][ 0 + 8 * q];
        half8 g1h1 = *(const half8*)&H1g[p ^ 1][col][32 + 8 * q];

        f32x4 br  = MFMA32(A0k1, g0h1, MFMA32(A0k0, g0h0, bR));
        f32x4 br2 = MFMA32(B0k1, g1h1, MFMA32(B0k0, g1h0, (f32x4){}));
        f32x4 bz  = MFMA32(A1k1, g0h1, MFMA32(A1k0, g0h0, bZ));
        f32x4 bz2 = MFMA32(B1k1, g1h1, MFMA32(B1k0, g1h0, (f32x4){}));
        f32x4 bxn = MFMA32(A2k1, g0h1, MFMA32(A2k0, g0h0, bXN));
        f32x4 bhn = MFMA32(B2k1, g1h1, MFMA32(B2k0, g1h0, bHN));
        br += br2; bz += bz2;

        half4 nh;
#pragma unroll
        for (int i = 0; i < 4; ++i) {
          const float r = sigm(br[i]);
          const float z = sigm(bz[i]);
          const float n = tanh_fast(fmaf(r, bhn[i], bxn[i]));
          hown[i] = fmaf(z, hown[i] - n, n);     // exact fp32 recurrence
          nh[i] = (_Float16)hown[i];
        }
        *(half4*)&H1g[p][col][16 * w + 4 * q] = nh;
      }
    }
    __syncthreads();   // the ONLY per-tick barrier
  }

  // ======== epilogue: out[s] = fcW · h1[s](t=511) + fcb ========
  if (!isL0) {
    f32x4 fw = *(const f32x4*)&fcW[bo];
    float partial = hown[0] * fw[0] + hown[1] * fw[1] +
                    hown[2] * fw[2] + hown[3] * fw[3];
    partial += __shfl_xor(partial, 16, 64);
    partial += __shfl_xor(partial, 32, 64);      // sum over q
    if ((t9 & 63) < 16) red[grp][w][col] = partial;
  }
  __syncthreads();
  if (tid < 16 * NGRP) {
    const int g = tid >> 4, s = tid & 15;
    out[blockIdx.x * (16 * NGRP) + g * 16 + s] =
        red[g][0][s] + red[g][1][s] + red[g][2][s] + red[g][3][s] + fcb[0];
  }
}

extern "C" void kernel_launch(void* const* d_in, const int* in_sizes, int n_in,
                              void* d_out, int out_size, void* d_ws, size_t ws_size,
                              hipStream_t stream) {
  (void)in_sizes; (void)n_in; (void)d_ws; (void)ws_size; (void)out_size;
  gru16<<<NBATCH / (16 * NGRP), 1024, 0, stream>>>(
      (const float*)d_in[0],  (const float*)d_in[1],
      (const float*)d_in[2],  (const float*)d_in[3],
      (const float*)d_in[4],  (const float*)d_in[5],
      (const float*)d_in[6],  (const float*)d_in[7],
      (const float*)d_in[8],  (const float*)d_in[9],
      (const float*)d_in[10],
      (float*)d_out);
}

// Round 11
// 398.040 us; speedup vs baseline: 1.5130x; 1.5130x over previous
//
#include <hip/hip_runtime.h>

#define NT 512
#define DIN 7
#define CTC 64
#define NBATCH 2048

typedef _Float16 half4 __attribute__((ext_vector_type(4)));
typedef _Float16 half8 __attribute__((ext_vector_type(8)));
typedef float    f32x4 __attribute__((ext_vector_type(4)));

#define MFMA32(A, B, C) __builtin_amdgcn_mfma_f32_16x16x32_f16((A), (B), (C), 0, 0, 0)

__device__ __forceinline__ float rcp_fast(float x) { return __builtin_amdgcn_rcpf(x); }
// weights pre-scaled by -log2(e): sigma(x) = 1/(1+2^(x'))
__device__ __forceinline__ float sigm2(float xs) { return rcp_fast(1.0f + exp2f(xs)); }
// weights pre-scaled by 2*log2(e): tanh(v) = 1 - 2/(1+2^(v'))
__device__ __forceinline__ float tanh2(float vs) {
  return fmaf(-2.0f, rcp_fast(1.0f + exp2f(vs)), 1.0f);
}

#define S_RZ (-1.4426950408889634f)   // -log2(e)
#define S_N  ( 2.8853900817779268f)   // 2*log2(e)

// 8 waves / block, 16 samples / block, 128 blocks (2 waves/SIMD on 128 CUs).
// Waves 0-3: layer0(tick k); waves 4-7: layer1(tick k-1). Operand-swapped
// MFMA (D = W.h^T, bias in C); h carried in fp32 registers by the owning
// lane; f16 copy exchanged via LDS in a TRANSPOSED layout
// [parity][k-octet][sample][8] so every wave B-fragment read is 64 lanes x
// consecutive 16B = conflict-free. exp2 scales folded into weights/biases.
// ONE barrier per tick.
__global__ __launch_bounds__(512, 1) void gru8(
    const float* __restrict__ x,     // [B][T][7]
    const float* __restrict__ Wih0,  // [192][7]
    const float* __restrict__ Whh0,  // [192][64]
    const float* __restrict__ bih0,  // [192]
    const float* __restrict__ bhh0,  // [192]
    const float* __restrict__ Wih1,  // [192][64]
    const float* __restrict__ Whh1,  // [192][64]
    const float* __restrict__ bih1,  // [192]
    const float* __restrict__ bhh1,  // [192]
    const float* __restrict__ fcW,   // [64]
    const float* __restrict__ fcb,   // [1]
    float* __restrict__ out)         // [2048]
{
  // h exchange buffers: [parity][k-octet][sample][8 f16] -> 4 KB each
  __shared__ __align__(16) _Float16 H0[2][8][16][8];
  __shared__ __align__(16) _Float16 H1[2][8][16][8];
  __shared__ __align__(16) _Float16 xb[16][CTC + 1][8]; // [sample][t+pad][8]
  __shared__ float red[4][16];                          // epilogue partials

  const int tid = threadIdx.x;
  const int col = tid & 15;        // sample / fragment col
  const int q   = (tid >> 4) & 3;  // k-octet / D-row quad
  const int wv  = tid >> 6;        // 0..7
  const bool isL0 = (wv < 4);
  const int w   = wv & 3;          // gate-tile group 0..3
  const int s0  = blockIdx.x * 16;

  for (int i = tid; i < 2 * 8 * 16 * 8; i += 512) {
    ((_Float16*)H0)[i] = (_Float16)0; ((_Float16*)H1)[i] = (_Float16)0;
  }

  const int gr = w * 16 + col, gz = (4 + w) * 16 + col, gn = (8 + w) * 16 + col;
  const int bo = w * 16 + 4 * q;   // this lane's D-row gate offset (within 64)

  // ---- biases in registers, exp2-scaled (C-operand of first MFMA) ----
  f32x4 bR, bZ, bXN, bHN;
  {
    const float* bi = isL0 ? bih0 : bih1;
    const float* bh = isL0 ? bhh0 : bhh1;
    f32x4 t1 = *(const f32x4*)&bi[bo],       t2 = *(const f32x4*)&bh[bo];
    bR = (t1 + t2) * S_RZ;
    t1 = *(const f32x4*)&bi[64 + bo];        t2 = *(const f32x4*)&bh[64 + bo];
    bZ = (t1 + t2) * S_RZ;
    bXN = *(const f32x4*)&bi[128 + bo] * S_N;
    bHN = *(const f32x4*)&bh[128 + bo] * S_N;
  }

  // ---- weight A-fragments, exp2-scaled: lane holds W[g][k=32kt+8q+i] ----
  half8 Wa0 = {}, Wa1 = {}, Wa2 = {};           // L0: Wih0 r/z/n (q==0 lanes)
  half8 A0k0, A0k1, A1k0, A1k1, A2k0, A2k1;     // L0: Whh0 | L1: Wih1
  half8 B0k0 = {}, B0k1 = {}, B1k0 = {}, B1k1 = {}, B2k0 = {}, B2k1 = {}; // L1: Whh1

#define LDW8(dst, W, g, kt, sc) do {                               \
    f32x4 _a = *(const f32x4*)&(W)[(g) * 64 + 32 * (kt) + 8 * q];  \
    f32x4 _b = *(const f32x4*)&(W)[(g) * 64 + 32 * (kt) + 8 * q + 4]; \
    half8 _h;                                                       \
    _h[0] = (_Float16)(_a[0] * (sc)); _h[1] = (_Float16)(_a[1] * (sc)); \
    _h[2] = (_Float16)(_a[2] * (sc)); _h[3] = (_Float16)(_a[3] * (sc)); \
    _h[4] = (_Float16)(_b[0] * (sc)); _h[5] = (_Float16)(_b[1] * (sc)); \
    _h[6] = (_Float16)(_b[2] * (sc)); _h[7] = (_Float16)(_b[3] * (sc)); \
    (dst) = _h;                                                     \
  } while (0)

  if (isL0) {
    if (q == 0) {
#pragma unroll
      for (int i = 0; i < DIN; ++i) {
        Wa0[i] = (_Float16)(Wih0[gr * DIN + i] * S_RZ);
        Wa1[i] = (_Float16)(Wih0[gz * DIN + i] * S_RZ);
        Wa2[i] = (_Float16)(Wih0[gn * DIN + i] * S_N);
      }
    }
    LDW8(A0k0, Whh0, gr, 0, S_RZ); LDW8(A0k1, Whh0, gr, 1, S_RZ);
    LDW8(A1k0, Whh0, gz, 0, S_RZ); LDW8(A1k1, Whh0, gz, 1, S_RZ);
    LDW8(A2k0, Whh0, gn, 0, S_N);  LDW8(A2k1, Whh0, gn, 1, S_N);
  } else {
    LDW8(A0k0, Wih1, gr, 0, S_RZ); LDW8(A0k1, Wih1, gr, 1, S_RZ);
    LDW8(A1k0, Wih1, gz, 0, S_RZ); LDW8(A1k1, Wih1, gz, 1, S_RZ);
    LDW8(A2k0, Wih1, gn, 0, S_N);  LDW8(A2k1, Wih1, gn, 1, S_N);
    LDW8(B0k0, Whh1, gr, 0, S_RZ); LDW8(B0k1, Whh1, gr, 1, S_RZ);
    LDW8(B1k0, Whh1, gz, 0, S_RZ); LDW8(B1k1, Whh1, gz, 1, S_RZ);
    LDW8(B2k0, Whh1, gn, 0, S_N);  LDW8(B2k1, Whh1, gn, 1, S_N);
  }
#undef LDW8
  __syncthreads();

  // lane's own h slice [16w+4q, +4), fp32, carried across ticks (exact)
  f32x4 hown = (f32x4){};
  // write target for h_new f16 copy in transposed layout:
  // h[16w+4q+i] -> H[parity][oct=2w+(q>>1)][col][4*(q&1)+i]
  const int woct = 2 * w + (q >> 1);
  const int woff = 4 * (q & 1);

  for (int k = 0; k <= NT; ++k) {
    const int p = k & 1;

    if ((k & (CTC - 1)) == 0 && k < NT) {
      // ---- stage CTC-step x chunk: 16 samples x CTC steps x 7 f32 -> f16 ----
      for (int e = tid; e < 16 * CTC; e += 512) {
        const int ss = e & 15, tt = e >> 4;
        const float* xp = x + ((size_t)(s0 + ss) * NT + k + tt) * DIN;
        half8 v = (half8){};
#pragma unroll
        for (int d = 0; d < DIN; ++d) v[d] = (_Float16)xp[d];
        *(half8*)&xb[ss][tt][0] = v;
      }
      __syncthreads();
    }

    if (isL0) {
      if (k < NT) {
        const int ti = k & (CTC - 1);
        // conflict-free: 64 lanes -> 64 consecutive 16B slots
        half8 hh0 = *(const half8*)&H0[p][q][col][0];
        half8 hh1 = *(const half8*)&H0[p][4 + q][col][0];
        // broadcast x fragment (same addr across q; A zeros kill k>=7 terms)
        half8 xf = *(const half8*)&xb[col][ti][0];

        f32x4 ar  = MFMA32(A0k0, hh0, MFMA32(Wa0, xf, bR));
        f32x4 ar2 = MFMA32(A0k1, hh1, (f32x4){});
        f32x4 az  = MFMA32(A1k0, hh0, MFMA32(Wa1, xf, bZ));
        f32x4 az2 = MFMA32(A1k1, hh1, (f32x4){});
        f32x4 axn = MFMA32(Wa2, xf, bXN);
        f32x4 ahn = MFMA32(A2k0, hh0, bHN);
        f32x4 ahn2 = MFMA32(A2k1, hh1, (f32x4){});
        ar += ar2; az += az2; ahn += ahn2;

        half4 nh;
#pragma unroll
        for (int i = 0; i < 4; ++i) {
          const float r = sigm2(ar[i]);
          const float z = sigm2(az[i]);
          const float n = tanh2(fmaf(r, ahn[i], axn[i]));
          hown[i] = fmaf(z, hown[i] - n, n);     // exact fp32 recurrence
          nh[i] = (_Float16)hown[i];
        }
        *(half4*)&H0[p ^ 1][woct][col][woff] = nh;
      }
    } else {
      if (k > 0) {
        half8 g0h0 = *(const half8*)&H0[p][q][col][0];
        half8 g0h1 = *(const half8*)&H0[p][4 + q][col][0];
        half8 g1h0 = *(const half8*)&H1[p ^ 1][q][col][0];
        half8 g1h1 = *(const half8*)&H1[p ^ 1][4 + q][col][0];

        f32x4 br  = MFMA32(A0k1, g0h1, MFMA32(A0k0, g0h0, bR));
        f32x4 br2 = MFMA32(B0k1, g1h1, MFMA32(B0k0, g1h0, (f32x4){}));
        f32x4 bz  = MFMA32(A1k1, g0h1, MFMA32(A1k0, g0h0, bZ));
        f32x4 bz2 = MFMA32(B1k1, g1h1, MFMA32(B1k0, g1h0, (f32x4){}));
        f32x4 bxn = MFMA32(A2k1, g0h1, MFMA32(A2k0, g0h0, bXN));
        f32x4 bhn = MFMA32(B2k1, g1h1, MFMA32(B2k0, g1h0, bHN));
        br += br2; bz += bz2;

        half4 nh;
#pragma unroll
        for (int i = 0; i < 4; ++i) {
          const float r = sigm2(br[i]);
          const float z = sigm2(bz[i]);
          const float n = tanh2(fmaf(r, bhn[i], bxn[i]));
          hown[i] = fmaf(z, hown[i] - n, n);     // exact fp32 recurrence
          nh[i] = (_Float16)hown[i];
        }
        *(half4*)&H1[p][woct][col][woff] = nh;
      }
    }
    __syncthreads();   // the ONLY per-tick barrier
  }

  // ======== epilogue: out[s] = fcW . h1[s](t=511) + fcb ========
  if (!isL0) {
    f32x4 fw = *(const f32x4*)&fcW[bo];
    float partial = hown[0] * fw[0] + hown[1] * fw[1] +
                    hown[2] * fw[2] + hown[3] * fw[3];
    partial += __shfl_xor(partial, 16, 64);
    partial += __shfl_xor(partial, 32, 64);      // sum over q
    if ((tid & 63) < 16) red[w][col] = partial;
  }
  __syncthreads();
  if (tid < 16) {
    out[s0 + tid] = red[0][tid] + red[1][tid] + red[2][tid] + red[3][tid] + fcb[0];
  }
}

extern "C" void kernel_launch(void* const* d_in, const int* in_sizes, int n_in,
                              void* d_out, int out_size, void* d_ws, size_t ws_size,
                              hipStream_t stream) {
  (void)in_sizes; (void)n_in; (void)d_ws; (void)ws_size; (void)out_size;
  gru8<<<NBATCH / 16, 512, 0, stream>>>(
      (const float*)d_in[0],  (const float*)d_in[1],
      (const float*)d_in[2],  (const float*)d_in[3],
      (const float*)d_in[4],  (const float*)d_in[5],
      (const float*)d_in[6],  (const float*)d_in[7],
      (const float*)d_in[8],  (const float*)d_in[9],
      (const float*)d_in[10],
      (float*)d_out);
}

// Round 12
// 300.745 us; speedup vs baseline: 2.0025x; 1.3235x over previous
//
#include <hip/hip_runtime.h>

#define NT 512
#define DIN 7
#define CTC 64
#define NBATCH 2048

typedef _Float16 half4 __attribute__((ext_vector_type(4)));
typedef _Float16 half8 __attribute__((ext_vector_type(8)));
typedef float    f32x4 __attribute__((ext_vector_type(4)));

#define MFMA32(A, B, C) __builtin_amdgcn_mfma_f32_16x16x32_f16((A), (B), (C), 0, 0, 0)

__device__ __forceinline__ float rcp_fast(float x) { return __builtin_amdgcn_rcpf(x); }
// raw v_exp_f32: computes 2^x in 1 instruction (precise exp2f lowers to a
// multi-inst denormal-fixup sequence -- the r11 regression)
__device__ __forceinline__ float exp2_raw(float x) {
  float r;
  asm("v_exp_f32 %0, %1" : "=v"(r) : "v"(x));
  return r;
}
// weights pre-scaled by -log2(e): sigma(x) = 1/(1+2^(x'))
__device__ __forceinline__ float sigm2(float xs) { return rcp_fast(1.0f + exp2_raw(xs)); }
// weights pre-scaled by 2*log2(e): tanh(v) = 1 - 2/(1+2^(v'))
__device__ __forceinline__ float tanh2(float vs) {
  return fmaf(-2.0f, rcp_fast(1.0f + exp2_raw(vs)), 1.0f);
}

#define S_RZ (-1.4426950408889634f)   // -log2(e)
#define S_N  ( 2.8853900817779268f)   // 2*log2(e)

// 8 waves / block, 16 samples / block, 128 blocks (2 waves/SIMD on 128 CUs).
// Waves 0-3: layer0(tick k); waves 4-7: layer1(tick k-1). Operand-swapped
// MFMA (D = W.h^T, bias in C); h carried in fp32 registers by the owning
// lane; f16 copy exchanged via LDS in a TRANSPOSED layout
// [parity][k-octet][sample][8] so every wave B-fragment read is 64 lanes x
// consecutive 16B = conflict-free. exp2 scales folded into weights/biases;
// transcendentals are raw v_exp_f32 + v_rcp_f32. ONE barrier per tick.
__global__ __launch_bounds__(512, 1) void gru8(
    const float* __restrict__ x,     // [B][T][7]
    const float* __restrict__ Wih0,  // [192][7]
    const float* __restrict__ Whh0,  // [192][64]
    const float* __restrict__ bih0,  // [192]
    const float* __restrict__ bhh0,  // [192]
    const float* __restrict__ Wih1,  // [192][64]
    const float* __restrict__ Whh1,  // [192][64]
    const float* __restrict__ bih1,  // [192]
    const float* __restrict__ bhh1,  // [192]
    const float* __restrict__ fcW,   // [64]
    const float* __restrict__ fcb,   // [1]
    float* __restrict__ out)         // [2048]
{
  // h exchange buffers: [parity][k-octet][sample][8 f16] -> 4 KB each
  __shared__ __align__(16) _Float16 H0[2][8][16][8];
  __shared__ __align__(16) _Float16 H1[2][8][16][8];
  __shared__ __align__(16) _Float16 xb[16][CTC + 1][8]; // [sample][t+pad][8]
  __shared__ float red[4][16];                          // epilogue partials

  const int tid = threadIdx.x;
  const int col = tid & 15;        // sample / fragment col
  const int q   = (tid >> 4) & 3;  // k-octet / D-row quad
  const int wv  = tid >> 6;        // 0..7
  const bool isL0 = (wv < 4);
  const int w   = wv & 3;          // gate-tile group 0..3
  const int s0  = blockIdx.x * 16;

  for (int i = tid; i < 2 * 8 * 16 * 8; i += 512) {
    ((_Float16*)H0)[i] = (_Float16)0; ((_Float16*)H1)[i] = (_Float16)0;
  }

  const int gr = w * 16 + col, gz = (4 + w) * 16 + col, gn = (8 + w) * 16 + col;
  const int bo = w * 16 + 4 * q;   // this lane's D-row gate offset (within 64)

  // ---- biases in registers, exp2-scaled (C-operand of first MFMA) ----
  f32x4 bR, bZ, bXN, bHN;
  {
    const float* bi = isL0 ? bih0 : bih1;
    const float* bh = isL0 ? bhh0 : bhh1;
    f32x4 t1 = *(const f32x4*)&bi[bo],       t2 = *(const f32x4*)&bh[bo];
    bR = (t1 + t2) * S_RZ;
    t1 = *(const f32x4*)&bi[64 + bo];        t2 = *(const f32x4*)&bh[64 + bo];
    bZ = (t1 + t2) * S_RZ;
    bXN = *(const f32x4*)&bi[128 + bo] * S_N;
    bHN = *(const f32x4*)&bh[128 + bo] * S_N;
  }

  // ---- weight A-fragments, exp2-scaled: lane holds W[g][k=32kt+8q+i] ----
  half8 Wa0 = {}, Wa1 = {}, Wa2 = {};           // L0: Wih0 r/z/n (q==0 lanes)
  half8 A0k0, A0k1, A1k0, A1k1, A2k0, A2k1;     // L0: Whh0 | L1: Wih1
  half8 B0k0 = {}, B0k1 = {}, B1k0 = {}, B1k1 = {}, B2k0 = {}, B2k1 = {}; // L1: Whh1

#define LDW8(dst, W, g, kt, sc) do {                               \
    f32x4 _a = *(const f32x4*)&(W)[(g) * 64 + 32 * (kt) + 8 * q];  \
    f32x4 _b = *(const f32x4*)&(W)[(g) * 64 + 32 * (kt) + 8 * q + 4]; \
    half8 _h;                                                       \
    _h[0] = (_Float16)(_a[0] * (sc)); _h[1] = (_Float16)(_a[1] * (sc)); \
    _h[2] = (_Float16)(_a[2] * (sc)); _h[3] = (_Float16)(_a[3] * (sc)); \
    _h[4] = (_Float16)(_b[0] * (sc)); _h[5] = (_Float16)(_b[1] * (sc)); \
    _h[6] = (_Float16)(_b[2] * (sc)); _h[7] = (_Float16)(_b[3] * (sc)); \
    (dst) = _h;                                                     \
  } while (0)

  if (isL0) {
    if (q == 0) {
#pragma unroll
      for (int i = 0; i < DIN; ++i) {
        Wa0[i] = (_Float16)(Wih0[gr * DIN + i] * S_RZ);
        Wa1[i] = (_Float16)(Wih0[gz * DIN + i] * S_RZ);
        Wa2[i] = (_Float16)(Wih0[gn * DIN + i] * S_N);
      }
    }
    LDW8(A0k0, Whh0, gr, 0, S_RZ); LDW8(A0k1, Whh0, gr, 1, S_RZ);
    LDW8(A1k0, Whh0, gz, 0, S_RZ); LDW8(A1k1, Whh0, gz, 1, S_RZ);
    LDW8(A2k0, Whh0, gn, 0, S_N);  LDW8(A2k1, Whh0, gn, 1, S_N);
  } else {
    LDW8(A0k0, Wih1, gr, 0, S_RZ); LDW8(A0k1, Wih1, gr, 1, S_RZ);
    LDW8(A1k0, Wih1, gz, 0, S_RZ); LDW8(A1k1, Wih1, gz, 1, S_RZ);
    LDW8(A2k0, Wih1, gn, 0, S_N);  LDW8(A2k1, Wih1, gn, 1, S_N);
    LDW8(B0k0, Whh1, gr, 0, S_RZ); LDW8(B0k1, Whh1, gr, 1, S_RZ);
    LDW8(B1k0, Whh1, gz, 0, S_RZ); LDW8(B1k1, Whh1, gz, 1, S_RZ);
    LDW8(B2k0, Whh1, gn, 0, S_N);  LDW8(B2k1, Whh1, gn, 1, S_N);
  }
#undef LDW8
  __syncthreads();

  // lane's own h slice [16w+4q, +4), fp32, carried across ticks (exact)
  f32x4 hown = (f32x4){};
  // write target for h_new f16 copy in transposed layout:
  // h[16w+4q+i] -> H[parity][oct=2w+(q>>1)][col][4*(q&1)+i]
  const int woct = 2 * w + (q >> 1);
  const int woff = 4 * (q & 1);

  for (int k = 0; k <= NT; ++k) {
    const int p = k & 1;

    if ((k & (CTC - 1)) == 0 && k < NT) {
      // ---- stage CTC-step x chunk: 16 samples x CTC steps x 7 f32 -> f16 ----
      for (int e = tid; e < 16 * CTC; e += 512) {
        const int ss = e & 15, tt = e >> 4;
        const float* xp = x + ((size_t)(s0 + ss) * NT + k + tt) * DIN;
        half8 v = (half8){};
#pragma unroll
        for (int d = 0; d < DIN; ++d) v[d] = (_Float16)xp[d];
        *(half8*)&xb[ss][tt][0] = v;
      }
      __syncthreads();
    }

    if (isL0) {
      if (k < NT) {
        const int ti = k & (CTC - 1);
        // conflict-free: 64 lanes -> 64 consecutive 16B slots
        half8 hh0 = *(const half8*)&H0[p][q][col][0];
        half8 hh1 = *(const half8*)&H0[p][4 + q][col][0];
        // broadcast x fragment (same addr across q; A zeros kill k>=7 terms)
        half8 xf = *(const half8*)&xb[col][ti][0];

        f32x4 ar  = MFMA32(A0k0, hh0, MFMA32(Wa0, xf, bR));
        f32x4 ar2 = MFMA32(A0k1, hh1, (f32x4){});
        f32x4 az  = MFMA32(A1k0, hh0, MFMA32(Wa1, xf, bZ));
        f32x4 az2 = MFMA32(A1k1, hh1, (f32x4){});
        f32x4 axn = MFMA32(Wa2, xf, bXN);
        f32x4 ahn = MFMA32(A2k0, hh0, bHN);
        f32x4 ahn2 = MFMA32(A2k1, hh1, (f32x4){});
        ar += ar2; az += az2; ahn += ahn2;

        half4 nh;
#pragma unroll
        for (int i = 0; i < 4; ++i) {
          const float r = sigm2(ar[i]);
          const float z = sigm2(az[i]);
          const float n = tanh2(fmaf(r, ahn[i], axn[i]));
          hown[i] = fmaf(z, hown[i] - n, n);     // exact fp32 recurrence
          nh[i] = (_Float16)hown[i];
        }
        *(half4*)&H0[p ^ 1][woct][col][woff] = nh;
      }
    } else {
      if (k > 0) {
        half8 g0h0 = *(const half8*)&H0[p][q][col][0];
        half8 g0h1 = *(const half8*)&H0[p][4 + q][col][0];
        half8 g1h0 = *(const half8*)&H1[p ^ 1][q][col][0];
        half8 g1h1 = *(const half8*)&H1[p ^ 1][4 + q][col][0];

        f32x4 br  = MFMA32(A0k1, g0h1, MFMA32(A0k0, g0h0, bR));
        f32x4 br2 = MFMA32(B0k1, g1h1, MFMA32(B0k0, g1h0, (f32x4){}));
        f32x4 bz  = MFMA32(A1k1, g0h1, MFMA32(A1k0, g0h0, bZ));
        f32x4 bz2 = MFMA32(B1k1, g1h1, MFMA32(B1k0, g1h0, (f32x4){}));
        f32x4 bxn = MFMA32(A2k1, g0h1, MFMA32(A2k0, g0h0, bXN));
        f32x4 bhn = MFMA32(B2k1, g1h1, MFMA32(B2k0, g1h0, bHN));
        br += br2; bz += bz2;

        half4 nh;
#pragma unroll
        for (int i = 0; i < 4; ++i) {
          const float r = sigm2(br[i]);
          const float z = sigm2(bz[i]);
          const float n = tanh2(fmaf(r, bhn[i], bxn[i]));
          hown[i] = fmaf(z, hown[i] - n, n);     // exact fp32 recurrence
          nh[i] = (_Float16)hown[i];
        }
        *(half4*)&H1[p][woct][col][woff] = nh;
      }
    }
    __syncthreads();   // the ONLY per-tick barrier
  }

  // ======== epilogue: out[s] = fcW . h1[s](t=511) + fcb ========
  if (!isL0) {
    f32x4 fw = *(const f32x4*)&fcW[bo];
    float partial = hown[0] * fw[0] + hown[1] * fw[1] +
                    hown[2] * fw[2] + hown[3] * fw[3];
    partial += __shfl_xor(partial, 16, 64);
    partial += __shfl_xor(partial, 32, 64);      // sum over q
    if ((tid & 63) < 16) red[w][col] = partial;
  }
  __syncthreads();
  if (tid < 16) {
    out[s0 + tid] = red[0][tid] + red[1][tid] + red[2][tid] + red[3][tid] + fcb[0];
  }
}

extern "C" void kernel_launch(void* const* d_in, const int* in_sizes, int n_in,
                              void* d_out, int out_size, void* d_ws, size_t ws_size,
                              hipStream_t stream) {
  (void)in_sizes; (void)n_in; (void)d_ws; (void)ws_size; (void)out_size;
  gru8<<<NBATCH / 16, 512, 0, stream>>>(
      (const float*)d_in[0],  (const float*)d_in[1],
      (const float*)d_in[2],  (const float*)d_in[3],
      (const float*)d_in[4],  (const float*)d_in[5],
      (const float*)d_in[6],  (const float*)d_in[7],
      (const float*)d_in[8],  (const float*)d_in[9],
      (const float*)d_in[10],
      (float*)d_out);
}

// Round 14
// 276.344 us; speedup vs baseline: 2.1793x; 1.0883x over previous
//
#include <hip/hip_runtime.h>

#define NT 512
#define DIN 7
#define CTC 64
#define NCH (NT / CTC)
#define NBATCH 2048

typedef _Float16 half4 __attribute__((ext_vector_type(4)));
typedef _Float16 half8 __attribute__((ext_vector_type(8)));
typedef float    f32x4 __attribute__((ext_vector_type(4)));

#define MFMA32(A, B, C) __builtin_amdgcn_mfma_f32_16x16x32_f16((A), (B), (C), 0, 0, 0)

__device__ __forceinline__ float rcp_fast(float x) { return __builtin_amdgcn_rcpf(x); }
// raw v_exp_f32: 2^x in one instruction (precise exp2f = multi-inst fixup)
__device__ __forceinline__ float exp2_raw(float x) {
  float r;
  asm("v_exp_f32 %0, %1" : "=v"(r) : "v"(x));
  return r;
}
// weights pre-scaled by -log2(e): sigma(x) = 1/(1+2^(x'))
__device__ __forceinline__ float sigm2(float xs) { return rcp_fast(1.0f + exp2_raw(xs)); }
// weights pre-scaled by 2*log2(e): tanh(v) = 1 - 2/(1+2^(v'))
__device__ __forceinline__ float tanh2(float vs) {
  return fmaf(-2.0f, rcp_fast(1.0f + exp2_raw(vs)), 1.0f);
}

// pack 4 floats -> half4 via v_cvt_pkrtz_f16_f32 (bit-cast fixes clang type)
__device__ __forceinline__ half4 pack_h4(float a, float b, float c, float d) {
  unsigned int lo = __builtin_bit_cast(unsigned int, __builtin_amdgcn_cvt_pkrtz(a, b));
  unsigned int hi = __builtin_bit_cast(unsigned int, __builtin_amdgcn_cvt_pkrtz(c, d));
  unsigned long long u = ((unsigned long long)hi << 32) | lo;
  return __builtin_bit_cast(half4, u);
}

#define S_RZ (-1.4426950408889634f)   // -log2(e)
#define S_N  ( 2.8853900817779268f)   // 2*log2(e)

// 8 waves / block, 16 samples / block, 128 blocks (2 waves/SIMD on 128 CUs).
// Waves 0-3: layer0(tick k); waves 4-7: layer1(tick k-1). Operand-swapped
// MFMA (D = W.h^T, bias in C); h carried in fp32 registers by the owning
// lane; f16 copy exchanged via LDS, transposed layout [parity][oct][sample][8]
// -> conflict-free b128 reads. exp2 scales folded into weights; raw v_exp_f32.
// This round: x-prefetch out of the post-barrier LDS burst, setprio around
// MFMA clusters (role-diverse waves per SIMD), cvt_pkrtz f16 packing,
// chunk-outer loop + peeled final L1 tick. ONE barrier per tick.
__global__ __launch_bounds__(512, 1) void gru8(
    const float* __restrict__ x,     // [B][T][7]
    const float* __restrict__ Wih0,  // [192][7]
    const float* __restrict__ Whh0,  // [192][64]
    const float* __restrict__ bih0,  // [192]
    const float* __restrict__ bhh0,  // [192]
    const float* __restrict__ Wih1,  // [192][64]
    const float* __restrict__ Whh1,  // [192][64]
    const float* __restrict__ bih1,  // [192]
    const float* __restrict__ bhh1,  // [192]
    const float* __restrict__ fcW,   // [64]
    const float* __restrict__ fcb,   // [1]
    float* __restrict__ out)         // [2048]
{
  __shared__ __align__(16) _Float16 H0[2][8][16][8];    // [parity][oct][sample][8]
  __shared__ __align__(16) _Float16 H1[2][8][16][8];
  __shared__ __align__(16) _Float16 xb[16][CTC + 1][8]; // [sample][t+pad][8]
  __shared__ float red[4][16];

  const int tid = threadIdx.x;
  const int col = tid & 15;        // sample / fragment col
  const int q   = (tid >> 4) & 3;  // k-octet / D-row quad
  const int wv  = tid >> 6;        // 0..7
  const bool isL0 = (wv < 4);
  const int w   = wv & 3;          // gate-tile group 0..3
  const int s0  = blockIdx.x * 16;

  for (int i = tid; i < 2 * 8 * 16 * 8; i += 512) {
    ((_Float16*)H0)[i] = (_Float16)0; ((_Float16*)H1)[i] = (_Float16)0;
  }

  const int gr = w * 16 + col, gz = (4 + w) * 16 + col, gn = (8 + w) * 16 + col;
  const int bo = w * 16 + 4 * q;

  // ---- biases in registers, exp2-scaled ----
  f32x4 bR, bZ, bXN, bHN;
  {
    const float* bi = isL0 ? bih0 : bih1;
    const float* bh = isL0 ? bhh0 : bhh1;
    f32x4 t1 = *(const f32x4*)&bi[bo],       t2 = *(const f32x4*)&bh[bo];
    bR = (t1 + t2) * S_RZ;
    t1 = *(const f32x4*)&bi[64 + bo];        t2 = *(const f32x4*)&bh[64 + bo];
    bZ = (t1 + t2) * S_RZ;
    bXN = *(const f32x4*)&bi[128 + bo] * S_N;
    bHN = *(const f32x4*)&bh[128 + bo] * S_N;
  }

  // ---- weight A-fragments, exp2-scaled ----
  half8 Wa0 = {}, Wa1 = {}, Wa2 = {};
  half8 A0k0, A0k1, A1k0, A1k1, A2k0, A2k1;
  half8 B0k0 = {}, B0k1 = {}, B1k0 = {}, B1k1 = {}, B2k0 = {}, B2k1 = {};

#define LDW8(dst, W, g, kt, sc) do {                               \
    f32x4 _a = *(const f32x4*)&(W)[(g) * 64 + 32 * (kt) + 8 * q];  \
    f32x4 _b = *(const f32x4*)&(W)[(g) * 64 + 32 * (kt) + 8 * q + 4]; \
    half8 _h;                                                       \
    _h[0] = (_Float16)(_a[0] * (sc)); _h[1] = (_Float16)(_a[1] * (sc)); \
    _h[2] = (_Float16)(_a[2] * (sc)); _h[3] = (_Float16)(_a[3] * (sc)); \
    _h[4] = (_Float16)(_b[0] * (sc)); _h[5] = (_Float16)(_b[1] * (sc)); \
    _h[6] = (_Float16)(_b[2] * (sc)); _h[7] = (_Float16)(_b[3] * (sc)); \
    (dst) = _h;                                                     \
  } while (0)

  if (isL0) {
    if (q == 0) {
#pragma unroll
      for (int i = 0; i < DIN; ++i) {
        Wa0[i] = (_Float16)(Wih0[gr * DIN + i] * S_RZ);
        Wa1[i] = (_Float16)(Wih0[gz * DIN + i] * S_RZ);
        Wa2[i] = (_Float16)(Wih0[gn * DIN + i] * S_N);
      }
    }
    LDW8(A0k0, Whh0, gr, 0, S_RZ); LDW8(A0k1, Whh0, gr, 1, S_RZ);
    LDW8(A1k0, Whh0, gz, 0, S_RZ); LDW8(A1k1, Whh0, gz, 1, S_RZ);
    LDW8(A2k0, Whh0, gn, 0, S_N);  LDW8(A2k1, Whh0, gn, 1, S_N);
  } else {
    LDW8(A0k0, Wih1, gr, 0, S_RZ); LDW8(A0k1, Wih1, gr, 1, S_RZ);
    LDW8(A1k0, Wih1, gz, 0, S_RZ); LDW8(A1k1, Wih1, gz, 1, S_RZ);
    LDW8(A2k0, Wih1, gn, 0, S_N);  LDW8(A2k1, Wih1, gn, 1, S_N);
    LDW8(B0k0, Whh1, gr, 0, S_RZ); LDW8(B0k1, Whh1, gr, 1, S_RZ);
    LDW8(B1k0, Whh1, gz, 0, S_RZ); LDW8(B1k1, Whh1, gz, 1, S_RZ);
    LDW8(B2k0, Whh1, gn, 0, S_N);  LDW8(B2k1, Whh1, gn, 1, S_N);
  }
#undef LDW8

  // lane's own h slice [16w+4q, +4), fp32, carried across ticks (exact)
  f32x4 hown = (f32x4){};
  const int woct = 2 * w + (q >> 1);
  const int woff = 4 * (q & 1);

  half8 xf_pref = (half8){};

  for (int m = 0; m < NCH; ++m) {
    __syncthreads();                 // xb free (covers initial H zero-init too)
    // ---- stage chunk m: 16 samples x 64 steps x 7 f32 -> f16 ----
    for (int e = tid; e < 16 * CTC; e += 512) {
      const int ss = e & 15, tt = e >> 4;
      const float* xp = x + ((size_t)(s0 + ss) * NT + m * CTC + tt) * DIN;
      half8 v = (half8){};
#pragma unroll
      for (int d = 0; d < DIN; ++d) v[d] = (_Float16)xp[d];
      *(half8*)&xb[ss][tt][0] = v;
    }
    __syncthreads();

    for (int ti = 0; ti < CTC; ++ti) {
      const int k = m * CTC + ti;
      const int p = ti & 1;          // CTC even -> parity == ti&1

      if (isL0) {
        half8 hh0 = *(const half8*)&H0[p][q][col][0];
        half8 hh1 = *(const half8*)&H0[p][4 + q][col][0];
        half8 xf = (ti == 0) ? *(const half8*)&xb[col][0][0] : xf_pref;

        __builtin_amdgcn_s_setprio(1);
        f32x4 ar  = MFMA32(A0k0, hh0, MFMA32(Wa0, xf, bR));
        f32x4 ar2 = MFMA32(A0k1, hh1, (f32x4){});
        f32x4 az  = MFMA32(A1k0, hh0, MFMA32(Wa1, xf, bZ));
        f32x4 az2 = MFMA32(A1k1, hh1, (f32x4){});
        f32x4 axn = MFMA32(Wa2, xf, bXN);
        f32x4 ahn = MFMA32(A2k0, hh0, bHN);
        f32x4 ahn2 = MFMA32(A2k1, hh1, (f32x4){});
        __builtin_amdgcn_s_setprio(0);

        // prefetch next tick's x fragment (pad row at ti=63: read, unused)
        xf_pref = *(const half8*)&xb[col][ti + 1][0];

        ar += ar2; az += az2; ahn += ahn2;
        float h0c, h1c, h2c, h3c;
        {
          const float r0 = sigm2(ar[0]), z0 = sigm2(az[0]);
          const float n0 = tanh2(fmaf(r0, ahn[0], axn[0]));
          h0c = fmaf(z0, hown[0] - n0, n0);
          const float r1 = sigm2(ar[1]), z1 = sigm2(az[1]);
          const float n1 = tanh2(fmaf(r1, ahn[1], axn[1]));
          h1c = fmaf(z1, hown[1] - n1, n1);
          const float r2 = sigm2(ar[2]), z2 = sigm2(az[2]);
          const float n2 = tanh2(fmaf(r2, ahn[2], axn[2]));
          h2c = fmaf(z2, hown[2] - n2, n2);
          const float r3 = sigm2(ar[3]), z3 = sigm2(az[3]);
          const float n3 = tanh2(fmaf(r3, ahn[3], axn[3]));
          h3c = fmaf(z3, hown[3] - n3, n3);
        }
        hown[0] = h0c; hown[1] = h1c; hown[2] = h2c; hown[3] = h3c;
        *(half4*)&H0[p ^ 1][woct][col][woff] = pack_h4(h0c, h1c, h2c, h3c);
      } else {
        if (k > 0) {
          half8 g0h0 = *(const half8*)&H0[p][q][col][0];
          half8 g0h1 = *(const half8*)&H0[p][4 + q][col][0];
          half8 g1h0 = *(const half8*)&H1[p ^ 1][q][col][0];
          half8 g1h1 = *(const half8*)&H1[p ^ 1][4 + q][col][0];

          __builtin_amdgcn_s_setprio(1);
          f32x4 br  = MFMA32(A0k1, g0h1, MFMA32(A0k0, g0h0, bR));
          f32x4 br2 = MFMA32(B0k1, g1h1, MFMA32(B0k0, g1h0, (f32x4){}));
          f32x4 bz  = MFMA32(A1k1, g0h1, MFMA32(A1k0, g0h0, bZ));
          f32x4 bz2 = MFMA32(B1k1, g1h1, MFMA32(B1k0, g1h0, (f32x4){}));
          f32x4 bxn = MFMA32(A2k1, g0h1, MFMA32(A2k0, g0h0, bXN));
          f32x4 bhn = MFMA32(B2k1, g1h1, MFMA32(B2k0, g1h0, bHN));
          __builtin_amdgcn_s_setprio(0);
          br += br2; bz += bz2;

          float h0c, h1c, h2c, h3c;
          {
            const float r0 = sigm2(br[0]), z0 = sigm2(bz[0]);
            const float n0 = tanh2(fmaf(r0, bhn[0], bxn[0]));
            h0c = fmaf(z0, hown[0] - n0, n0);
            const float r1 = sigm2(br[1]), z1 = sigm2(bz[1]);
            const float n1 = tanh2(fmaf(r1, bhn[1], bxn[1]));
            h1c = fmaf(z1, hown[1] - n1, n1);
            const float r2 = sigm2(br[2]), z2 = sigm2(bz[2]);
            const float n2 = tanh2(fmaf(r2, bhn[2], bxn[2]));
            h2c = fmaf(z2, hown[2] - n2, n2);
            const float r3 = sigm2(br[3]), z3 = sigm2(bz[3]);
            const float n3 = tanh2(fmaf(r3, bhn[3], bxn[3]));
            h3c = fmaf(z3, hown[3] - n3, n3);
          }
          hown[0] = h0c; hown[1] = h1c; hown[2] = h2c; hown[3] = h3c;
          *(half4*)&H1[p][woct][col][woff] = pack_h4(h0c, h1c, h2c, h3c);
        }
      }
      __syncthreads();   // the ONLY per-tick barrier
    }
  }

  // ======== peeled final tick: L1 computes h1(511) in registers only ========
  // k = 512 -> p = 0: h0(511) in H0[0], h1(510) in H1[1]; no LDS write needed.
  if (!isL0) {
    half8 g0h0 = *(const half8*)&H0[0][q][col][0];
    half8 g0h1 = *(const half8*)&H0[0][4 + q][col][0];
    half8 g1h0 = *(const half8*)&H1[1][q][col][0];
    half8 g1h1 = *(const half8*)&H1[1][4 + q][col][0];

    f32x4 br  = MFMA32(A0k1, g0h1, MFMA32(A0k0, g0h0, bR));
    f32x4 br2 = MFMA32(B0k1, g1h1, MFMA32(B0k0, g1h0, (f32x4){}));
    f32x4 bz  = MFMA32(A1k1, g0h1, MFMA32(A1k0, g0h0, bZ));
    f32x4 bz2 = MFMA32(B1k1, g1h1, MFMA32(B1k0, g1h0, (f32x4){}));
    f32x4 bxn = MFMA32(A2k1, g0h1, MFMA32(A2k0, g0h0, bXN));
    f32x4 bhn = MFMA32(B2k1, g1h1, MFMA32(B2k0, g1h0, bHN));
    br += br2; bz += bz2;

#pragma unroll
    for (int i = 0; i < 4; ++i) {
      const float r = sigm2(br[i]);
      const float z = sigm2(bz[i]);
      const float n = tanh2(fmaf(r, bhn[i], bxn[i]));
      hown[i] = fmaf(z, hown[i] - n, n);
    }
    // out[s] = fcW . h1[s] + fcb
    f32x4 fw = *(const f32x4*)&fcW[bo];
    float partial = hown[0] * fw[0] + hown[1] * fw[1] +
                    hown[2] * fw[2] + hown[3] * fw[3];
    partial += __shfl_xor(partial, 16, 64);
    partial += __shfl_xor(partial, 32, 64);
    if ((tid & 63) < 16) red[w][col] = partial;
  }
  __syncthreads();
  if (tid < 16) {
    out[s0 + tid] = red[0][tid] + red[1][tid] + red[2][tid] + red[3][tid] + fcb[0];
  }
}

extern "C" void kernel_launch(void* const* d_in, const int* in_sizes, int n_in,
                              void* d_out, int out_size, void* d_ws, size_t ws_size,
                              hipStream_t stream) {
  (void)in_sizes; (void)n_in; (void)d_ws; (void)ws_size; (void)out_size;
  gru8<<<NBATCH / 16, 512, 0, stream>>>(
      (const float*)d_in[0],  (const float*)d_in[1],
      (const float*)d_in[2],  (const float*)d_in[3],
      (const float*)d_in[4],  (const float*)d_in[5],
      (const float*)d_in[6],  (const float*)d_in[7],
      (const float*)d_in[8],  (const float*)d_in[9],
      (const float*)d_in[10],
      (float*)d_out);
}

// Round 15
// 269.882 us; speedup vs baseline: 2.2315x; 1.0239x over previous
//
#include <hip/hip_runtime.h>

#define NT 512
#define DIN 7
#define CTC 64
#define NCH (NT / CTC)
#define NBATCH 2048

typedef _Float16 half4 __attribute__((ext_vector_type(4)));
typedef _Float16 half8 __attribute__((ext_vector_type(8)));
typedef float    f32x4 __attribute__((ext_vector_type(4)));

#define MFMA32(A, B, C) __builtin_amdgcn_mfma_f32_16x16x32_f16((A), (B), (C), 0, 0, 0)

__device__ __forceinline__ float rcp_fast(float x) { return __builtin_amdgcn_rcpf(x); }
__device__ __forceinline__ float exp2_raw(float x) {
  float r;
  asm("v_exp_f32 %0, %1" : "=v"(r) : "v"(x));
  return r;
}
__device__ __forceinline__ float sigm2(float xs) { return rcp_fast(1.0f + exp2_raw(xs)); }
__device__ __forceinline__ float tanh2(float vs) {
  return fmaf(-2.0f, rcp_fast(1.0f + exp2_raw(vs)), 1.0f);
}

__device__ __forceinline__ half4 pack_h4(float a, float b, float c, float d) {
  unsigned int lo = __builtin_bit_cast(unsigned int, __builtin_amdgcn_cvt_pkrtz(a, b));
  unsigned int hi = __builtin_bit_cast(unsigned int, __builtin_amdgcn_cvt_pkrtz(c, d));
  unsigned long long u = ((unsigned long long)hi << 32) | lo;
  return __builtin_bit_cast(half4, u);
}

#define S_RZ (-1.4426950408889634f)   // -log2(e)
#define S_N  ( 2.8853900817779268f)   // 2*log2(e)

// 8 waves / block, 16 samples / block, 128 blocks (2 waves/SIMD on 128 CUs).
// Waves 0-3: layer0(tick k); waves 4-7: layer1(tick k-1). Operand-swapped
// MFMA (D = W.h^T, bias in C); h carried in fp32 registers by the owning
// lane; f16 copy exchanged via LDS, transposed layout [parity][oct][sample][8]
// -> conflict-free b128 reads. exp2 scales folded into weights; raw v_exp_f32.
// This round: tick loop unrolled x2 with COMPILE-TIME parity (LDS addresses
// become base + immediate offsets), chunk-entry barrier elided, xf prefetch
// double-buffered in registers. ONE barrier per tick.
__global__ __launch_bounds__(512, 1) void gru8(
    const float* __restrict__ x,     // [B][T][7]
    const float* __restrict__ Wih0,  // [192][7]
    const float* __restrict__ Whh0,  // [192][64]
    const float* __restrict__ bih0,  // [192]
    const float* __restrict__ bhh0,  // [192]
    const float* __restrict__ Wih1,  // [192][64]
    const float* __restrict__ Whh1,  // [192][64]
    const float* __restrict__ bih1,  // [192]
    const float* __restrict__ bhh1,  // [192]
    const float* __restrict__ fcW,   // [64]
    const float* __restrict__ fcb,   // [1]
    float* __restrict__ out)         // [2048]
{
  __shared__ __align__(16) _Float16 H0[2][8][16][8];    // [parity][oct][sample][8]
  __shared__ __align__(16) _Float16 H1[2][8][16][8];
  __shared__ __align__(16) _Float16 xb[16][CTC + 1][8]; // [sample][t+pad][8]
  __shared__ float red[4][16];

  const int tid = threadIdx.x;
  const int col = tid & 15;        // sample / fragment col
  const int q   = (tid >> 4) & 3;  // k-octet / D-row quad
  const int wv  = tid >> 6;        // 0..7
  const bool isL0 = (wv < 4);
  const int w   = wv & 3;          // gate-tile group 0..3
  const int s0  = blockIdx.x * 16;

  for (int i = tid; i < 2 * 8 * 16 * 8; i += 512) {
    ((_Float16*)H0)[i] = (_Float16)0; ((_Float16*)H1)[i] = (_Float16)0;
  }

  const int gr = w * 16 + col, gz = (4 + w) * 16 + col, gn = (8 + w) * 16 + col;
  const int bo = w * 16 + 4 * q;

  // ---- biases in registers, exp2-scaled ----
  f32x4 bR, bZ, bXN, bHN;
  {
    const float* bi = isL0 ? bih0 : bih1;
    const float* bh = isL0 ? bhh0 : bhh1;
    f32x4 t1 = *(const f32x4*)&bi[bo],       t2 = *(const f32x4*)&bh[bo];
    bR = (t1 + t2) * S_RZ;
    t1 = *(const f32x4*)&bi[64 + bo];        t2 = *(const f32x4*)&bh[64 + bo];
    bZ = (t1 + t2) * S_RZ;
    bXN = *(const f32x4*)&bi[128 + bo] * S_N;
    bHN = *(const f32x4*)&bh[128 + bo] * S_N;
  }

  // ---- weight A-fragments, exp2-scaled ----
  half8 Wa0 = {}, Wa1 = {}, Wa2 = {};
  half8 A0k0, A0k1, A1k0, A1k1, A2k0, A2k1;
  half8 B0k0 = {}, B0k1 = {}, B1k0 = {}, B1k1 = {}, B2k0 = {}, B2k1 = {};

#define LDW8(dst, W, g, kt, sc) do {                               \
    f32x4 _a = *(const f32x4*)&(W)[(g) * 64 + 32 * (kt) + 8 * q];  \
    f32x4 _b = *(const f32x4*)&(W)[(g) * 64 + 32 * (kt) + 8 * q + 4]; \
    half8 _h;                                                       \
    _h[0] = (_Float16)(_a[0] * (sc)); _h[1] = (_Float16)(_a[1] * (sc)); \
    _h[2] = (_Float16)(_a[2] * (sc)); _h[3] = (_Float16)(_a[3] * (sc)); \
    _h[4] = (_Float16)(_b[0] * (sc)); _h[5] = (_Float16)(_b[1] * (sc)); \
    _h[6] = (_Float16)(_b[2] * (sc)); _h[7] = (_Float16)(_b[3] * (sc)); \
    (dst) = _h;                                                     \
  } while (0)

  if (isL0) {
    if (q == 0) {
#pragma unroll
      for (int i = 0; i < DIN; ++i) {
        Wa0[i] = (_Float16)(Wih0[gr * DIN + i] * S_RZ);
        Wa1[i] = (_Float16)(Wih0[gz * DIN + i] * S_RZ);
        Wa2[i] = (_Float16)(Wih0[gn * DIN + i] * S_N);
      }
    }
    LDW8(A0k0, Whh0, gr, 0, S_RZ); LDW8(A0k1, Whh0, gr, 1, S_RZ);
    LDW8(A1k0, Whh0, gz, 0, S_RZ); LDW8(A1k1, Whh0, gz, 1, S_RZ);
    LDW8(A2k0, Whh0, gn, 0, S_N);  LDW8(A2k1, Whh0, gn, 1, S_N);
  } else {
    LDW8(A0k0, Wih1, gr, 0, S_RZ); LDW8(A0k1, Wih1, gr, 1, S_RZ);
    LDW8(A1k0, Wih1, gz, 0, S_RZ); LDW8(A1k1, Wih1, gz, 1, S_RZ);
    LDW8(A2k0, Wih1, gn, 0, S_N);  LDW8(A2k1, Wih1, gn, 1, S_N);
    LDW8(B0k0, Whh1, gr, 0, S_RZ); LDW8(B0k1, Whh1, gr, 1, S_RZ);
    LDW8(B1k0, Whh1, gz, 0, S_RZ); LDW8(B1k1, Whh1, gz, 1, S_RZ);
    LDW8(B2k0, Whh1, gn, 0, S_N);  LDW8(B2k1, Whh1, gn, 1, S_N);
  }
#undef LDW8

  // lane's own h slice [16w+4q, +4), fp32, carried across ticks (exact)
  f32x4 hown = (f32x4){};
  const int woct = 2 * w + (q >> 1);
  const int woff = 4 * (q & 1);

  // ---- tick bodies: parity P is a compile-time literal -> LDS addresses
  //      collapse to base VGPR + immediate offsets ----
#define L0_TICK(P, XFCUR, XFNXT, TIN) do {                                    \
    half8 hh0 = *(const half8*)&H0[P][q][col][0];                             \
    half8 hh1 = *(const half8*)&H0[P][4 + q][col][0];                         \
    __builtin_amdgcn_s_setprio(1);                                            \
    f32x4 ar  = MFMA32(A0k0, hh0, MFMA32(Wa0, XFCUR, bR));                    \
    f32x4 ar2 = MFMA32(A0k1, hh1, (f32x4){});                                 \
    f32x4 az  = MFMA32(A1k0, hh0, MFMA32(Wa1, XFCUR, bZ));                    \
    f32x4 az2 = MFMA32(A1k1, hh1, (f32x4){});                                 \
    f32x4 axn = MFMA32(Wa2, XFCUR, bXN);                                      \
    f32x4 ahn = MFMA32(A2k0, hh0, bHN);                                       \
    f32x4 ahn2 = MFMA32(A2k1, hh1, (f32x4){});                                \
    __builtin_amdgcn_s_setprio(0);                                            \
    XFNXT = *(const half8*)&xb[col][(TIN) + 1][0];                            \
    ar += ar2; az += az2; ahn += ahn2;                                        \
    const float r0 = sigm2(ar[0]), z0 = sigm2(az[0]);                         \
    const float n0 = tanh2(fmaf(r0, ahn[0], axn[0]));                         \
    const float h0c = fmaf(z0, hown[0] - n0, n0);                             \
    const float r1 = sigm2(ar[1]), z1 = sigm2(az[1]);                         \
    const float n1 = tanh2(fmaf(r1, ahn[1], axn[1]));                         \
    const float h1c = fmaf(z1, hown[1] - n1, n1);                             \
    const float r2 = sigm2(ar[2]), z2 = sigm2(az[2]);                         \
    const float n2 = tanh2(fmaf(r2, ahn[2], axn[2]));                         \
    const float h2c = fmaf(z2, hown[2] - n2, n2);                             \
    const float r3 = sigm2(ar[3]), z3 = sigm2(az[3]);                         \
    const float n3 = tanh2(fmaf(r3, ahn[3], axn[3]));                         \
    const float h3c = fmaf(z3, hown[3] - n3, n3);                             \
    hown[0] = h0c; hown[1] = h1c; hown[2] = h2c; hown[3] = h3c;               \
    *(half4*)&H0[(P) ^ 1][woct][col][woff] = pack_h4(h0c, h1c, h2c, h3c);     \
  } while (0)

#define L1_TICK(P) do {                                                       \
    half8 g0h0 = *(const half8*)&H0[P][q][col][0];                            \
    half8 g0h1 = *(const half8*)&H0[P][4 + q][col][0];                        \
    half8 g1h0 = *(const half8*)&H1[(P) ^ 1][q][col][0];                      \
    half8 g1h1 = *(const half8*)&H1[(P) ^ 1][4 + q][col][0];                  \
    __builtin_amdgcn_s_setprio(1);                                            \
    f32x4 br  = MFMA32(A0k1, g0h1, MFMA32(A0k0, g0h0, bR));                   \
    f32x4 br2 = MFMA32(B0k1, g1h1, MFMA32(B0k0, g1h0, (f32x4){}));            \
    f32x4 bz  = MFMA32(A1k1, g0h1, MFMA32(A1k0, g0h0, bZ));                   \
    f32x4 bz2 = MFMA32(B1k1, g1h1, MFMA32(B1k0, g1h0, (f32x4){}));            \
    f32x4 bxn = MFMA32(A2k1, g0h1, MFMA32(A2k0, g0h0, bXN));                  \
    f32x4 bhn = MFMA32(B2k1, g1h1, MFMA32(B2k0, g1h0, bHN));                  \
    __builtin_amdgcn_s_setprio(0);                                            \
    br += br2; bz += bz2;                                                     \
    const float r0 = sigm2(br[0]), z0 = sigm2(bz[0]);                         \
    const float n0 = tanh2(fmaf(r0, bhn[0], bxn[0]));                         \
    const float h0c = fmaf(z0, hown[0] - n0, n0);                             \
    const float r1 = sigm2(br[1]), z1 = sigm2(bz[1]);                         \
    const float n1 = tanh2(fmaf(r1, bhn[1], bxn[1]));                         \
    const float h1c = fmaf(z1, hown[1] - n1, n1);                             \
    const float r2 = sigm2(br[2]), z2 = sigm2(bz[2]);                         \
    const float n2 = tanh2(fmaf(r2, bhn[2], bxn[2]));                         \
    const float h2c = fmaf(z2, hown[2] - n2, n2);                             \
    const float r3 = sigm2(br[3]), z3 = sigm2(bz[3]);                         \
    const float n3 = tanh2(fmaf(r3, bhn[3], bxn[3]));                         \
    const float h3c = fmaf(z3, hown[3] - n3, n3);                             \
    hown[0] = h0c; hown[1] = h1c; hown[2] = h2c; hown[3] = h3c;               \
    *(half4*)&H1[P][woct][col][woff] = pack_h4(h0c, h1c, h2c, h3c);           \
  } while (0)

  for (int m = 0; m < NCH; ++m) {
    // stage chunk m; xb is free (previous ticks' barrier drained all reads,
    // including the last pad-row prefetch). Covers H zero-init before m=0.
    for (int e = tid; e < 16 * CTC; e += 512) {
      const int ss = e & 15, tt = e >> 4;
      const float* xp = x + ((size_t)(s0 + ss) * NT + m * CTC + tt) * DIN;
      half8 v = (half8){};
#pragma unroll
      for (int d = 0; d < DIN; ++d) v[d] = (_Float16)xp[d];
      *(half8*)&xb[ss][tt][0] = v;
    }
    __syncthreads();

    half8 xfA = (half8){}, xfB = (half8){};
    if (isL0) xfA = *(const half8*)&xb[col][0][0];

    for (int th = 0; th < CTC; th += 2) {
      if (isL0) {
        L0_TICK(0, xfA, xfB, th);
      } else if (m + th > 0) {   // k = m*CTC + th == 0 only at very first tick
        L1_TICK(0);
      }
      __syncthreads();
      if (isL0) {
        L0_TICK(1, xfB, xfA, th + 1);
      } else {
        L1_TICK(1);
      }
      __syncthreads();
    }
  }
#undef L0_TICK
#undef L1_TICK

  // ======== peeled final tick: L1 computes h1(511) in registers only ========
  // k = 512 -> parity 0: h0(511) in H0[0], h1(510) in H1[1]; no LDS write.
  if (!isL0) {
    half8 g0h0 = *(const half8*)&H0[0][q][col][0];
    half8 g0h1 = *(const half8*)&H0[0][4 + q][col][0];
    half8 g1h0 = *(const half8*)&H1[1][q][col][0];
    half8 g1h1 = *(const half8*)&H1[1][4 + q][col][0];

    f32x4 br  = MFMA32(A0k1, g0h1, MFMA32(A0k0, g0h0, bR));
    f32x4 br2 = MFMA32(B0k1, g1h1, MFMA32(B0k0, g1h0, (f32x4){}));
    f32x4 bz  = MFMA32(A1k1, g0h1, MFMA32(A1k0, g0h0, bZ));
    f32x4 bz2 = MFMA32(B1k1, g1h1, MFMA32(B1k0, g1h0, (f32x4){}));
    f32x4 bxn = MFMA32(A2k1, g0h1, MFMA32(A2k0, g0h0, bXN));
    f32x4 bhn = MFMA32(B2k1, g1h1, MFMA32(B2k0, g1h0, bHN));
    br += br2; bz += bz2;

#pragma unroll
    for (int i = 0; i < 4; ++i) {
      const float r = sigm2(br[i]);
      const float z = sigm2(bz[i]);
      const float n = tanh2(fmaf(r, bhn[i], bxn[i]));
      hown[i] = fmaf(z, hown[i] - n, n);
    }
    f32x4 fw = *(const f32x4*)&fcW[bo];
    float partial = hown[0] * fw[0] + hown[1] * fw[1] +
                    hown[2] * fw[2] + hown[3] * fw[3];
    partial += __shfl_xor(partial, 16, 64);
    partial += __shfl_xor(partial, 32, 64);
    if ((tid & 63) < 16) red[w][col] = partial;
  }
  __syncthreads();
  if (tid < 16) {
    out[s0 + tid] = red[0][tid] + red[1][tid] + red[2][tid] + red[3][tid] + fcb[0];
  }
}

extern "C" void kernel_launch(void* const* d_in, const int* in_sizes, int n_in,
                              void* d_out, int out_size, void* d_ws, size_t ws_size,
                              hipStream_t stream) {
  (void)in_sizes; (void)n_in; (void)d_ws; (void)ws_size; (void)out_size;
  gru8<<<NBATCH / 16, 512, 0, stream>>>(
      (const float*)d_in[0],  (const float*)d_in[1],
      (const float*)d_in[2],  (const float*)d_in[3],
      (const float*)d_in[4],  (const float*)d_in[5],
      (const float*)d_in[6],  (const float*)d_in[7],
      (const float*)d_in[8],  (const float*)d_in[9],
      (const float*)d_in[10],
      (float*)d_out);
}